// Round 5
// baseline (96.696 us; speedup 1.0000x reference)
//
#include <hip/hip_runtime.h>

#define HWC 4096
#define WC 64
#define HC 64
#define DC 256
#define BC 2
#define KKC 81

typedef _Float16 h2 __attribute__((ext_vector_type(2)));
typedef _Float16 h8 __attribute__((ext_vector_type(8)));

static __device__ inline float dot8(h8 v, h8 a, float s) {
#if __has_builtin(__builtin_amdgcn_fdot2)
    s = __builtin_amdgcn_fdot2((h2){v[0], v[1]}, (h2){a[0], a[1]}, s, false);
    s = __builtin_amdgcn_fdot2((h2){v[2], v[3]}, (h2){a[2], a[3]}, s, false);
    s = __builtin_amdgcn_fdot2((h2){v[4], v[5]}, (h2){a[4], a[5]}, s, false);
    s = __builtin_amdgcn_fdot2((h2){v[6], v[7]}, (h2){a[6], a[7]}, s, false);
#else
#pragma unroll
    for (int k = 0; k < 8; ++k) s += (float)v[k] * (float)a[k];
#endif
    return s;
}

// x += x[from other lane], 16-lane-row DPP; ctrl must be a literal.
#define DPP_ADD(x, ctrl) \
    ((x) + __int_as_float(__builtin_amdgcn_update_dpp(0, __float_as_int(x), (ctrl), 0xF, 0xF, true)))

// ------- transpose+cast f2 only: [B, D, HW] f32 -> [B, HW, D] f16 -------
__global__ __launch_bounds__(256) void transpose_h_k(const float* __restrict__ in0,
                                                     _Float16* __restrict__ out0) {
    __shared__ float tile[64][33];
    const int b = blockIdx.z;
    const float* in = in0 + (size_t)b * DC * HWC;
    _Float16* out = out0 + (size_t)b * HWC * DC;
    const int m0 = blockIdx.x * 32, d0 = blockIdx.y * 64;
    const int tid = threadIdx.x;

    const int tx = tid & 31, ty = tid >> 5;  // (m, d-group)
#pragma unroll
    for (int k = 0; k < 8; ++k)
        tile[ty + k * 8][tx] = in[(size_t)(d0 + ty + k * 8) * HWC + m0 + tx];
    __syncthreads();

    const int dx = tid & 7, my = tid >> 3;   // (d-octet, m)
    h8 v;
#pragma unroll
    for (int e = 0; e < 8; ++e) v[e] = (_Float16)tile[dx * 8 + e][my];
    *(h8*)(out + (size_t)(m0 + my) * DC + d0 + dx * 8) = v;
}

// ---------------- fused neighborhood-corr + bilinear ----------------
// One block per output pixel (b, hw). 16 groups x 16 lanes; each group computes
// one grid dot per iteration over the 10x10 integer patch (padded to 112 slots
// so all 7 iterations are branch-uniform). Loads are unconditional (clamped
// coords) so the compiler can pipeline them; validity applied via select.
// Group reduce = DPP (quad_perm x2, row_ror:4/8) — no LDS-pipe shuffles.
// RAFT quirk: out[n, i, j] samples at x = x_c + (i-4), y = y_c + (j-4).
__global__ __launch_bounds__(256) void corr_k(const float* __restrict__ f1,
                                              const _Float16* __restrict__ f2t,
                                              const float* __restrict__ coords,
                                              float* __restrict__ out) {
    __shared__ float Cs[112];   // Cs[yi*10+xi] = corr(y=iy0-4+yi, x=ix0-4+xi)
    __shared__ float f1s[DC];

    const int bid = blockIdx.x;
    // XCD swizzle: batch 0 -> XCDs 0..3, batch 1 -> XCDs 4..7 (per-batch 4MB f16
    // f2t fits the XCD group's L2)
    const int xcd = bid & 7;
    const int b = xcd >> 2;
    const int hw = ((bid >> 3) << 2) + (xcd & 3);

    const int tid = threadIdx.x;
    const int g = tid >> 4;    // group 0..15
    const int l = tid & 15;    // lane-in-group (= DPP row)

    // stage this pixel's f1 column (strided, once per block)
    f1s[tid] = f1[((size_t)b * DC + tid) * HWC + hw];

    const float x = coords[((size_t)b * 2 + 0) * HWC + hw];
    const float y = coords[((size_t)b * 2 + 1) * HWC + hw];
    const float x0f = floorf(x), y0f = floorf(y);
    const float wx = x - x0f, wy = y - y0f;
    const int ix0 = (int)x0f, iy0 = (int)y0f;
    __syncthreads();

    // per-lane f1 fragment (16 consecutive d) -> f16
    const float* fp = f1s + l * 16;
    h8 a0, a1;
#pragma unroll
    for (int e = 0; e < 8; ++e) { a0[e] = (_Float16)fp[e]; a1[e] = (_Float16)fp[8 + e]; }

    const h8* f2b = (const h8*)f2t + (size_t)b * HWC * 32;

#pragma unroll
    for (int it = 0; it < 7; ++it) {
        const int t = it * 16 + g;
        const int yi = t / 10, xi = t - yi * 10;
        const int gy = iy0 - 4 + yi, gx = ix0 - 4 + xi;
        const int gyc = min(max(gy, 0), HC - 1);
        const int gxc = min(max(gx, 0), WC - 1);
        const bool valid = ((unsigned)gy < (unsigned)HC) &
                           ((unsigned)gx < (unsigned)WC) & (t < 100);
        const h8* vp = f2b + (size_t)(gyc * WC + gxc) * 32 + l * 2;
        const h8 v0 = vp[0], v1 = vp[1];
        float s = dot8(v0, a0, 0.f);
        s = dot8(v1, a1, s);
        s = valid ? s : 0.f;
        s = DPP_ADD(s, 0xB1);   // quad_perm [1,0,3,2]  (xor 1)
        s = DPP_ADD(s, 0x4E);   // quad_perm [2,3,0,1]  (xor 2)
        s = DPP_ADD(s, 0x124);  // row_ror:4
        s = DPP_ADD(s, 0x128);  // row_ror:8
        if (l == 0) Cs[t] = s * 0.0625f;  // 1/sqrt(256)
    }
    __syncthreads();

    if (tid < KKC) {
        const int i = tid / 9, j = tid % 9;  // i walks x, j walks y (RAFT quirk)
        const float w00 = (1.f - wx) * (1.f - wy);
        const float w01 = wx * (1.f - wy);
        const float w10 = (1.f - wx) * wy;
        const float w11 = wx * wy;
        const float r = w00 * Cs[j * 10 + i]       + w01 * Cs[j * 10 + i + 1] +
                        w10 * Cs[(j + 1) * 10 + i] + w11 * Cs[(j + 1) * 10 + i + 1];
        out[((size_t)(b * KKC + tid)) * HWC + hw] = r;
    }
}

extern "C" void kernel_launch(void* const* d_in, const int* in_sizes, int n_in,
                              void* d_out, int out_size, void* d_ws, size_t ws_size,
                              hipStream_t stream) {
    const float* fmap1 = (const float*)d_in[0];
    const float* fmap2 = (const float*)d_in[1];
    const float* coords = (const float*)d_in[2];
    float* out = (float*)d_out;

    _Float16* f2t = (_Float16*)d_ws;  // [B, HW, D] f16 = 4 MB

    transpose_h_k<<<dim3(HWC / 32, DC / 64, BC), dim3(256), 0, stream>>>(fmap2, f2t);
    corr_k<<<dim3(BC * HWC), dim3(256), 0, stream>>>(fmap1, f2t, coords, out);
}

// Round 6
// 92.510 us; speedup vs baseline: 1.0453x; 1.0453x over previous
//
#include <hip/hip_runtime.h>

#define HWC 4096
#define WC 64
#define HC 64
#define DC 256
#define BC 2
#define KKC 81

typedef _Float16 h2 __attribute__((ext_vector_type(2)));
typedef _Float16 h8 __attribute__((ext_vector_type(8)));

static __device__ inline float dot8(h8 v, h8 a, float s) {
#if __has_builtin(__builtin_amdgcn_fdot2)
    s = __builtin_amdgcn_fdot2((h2){v[0], v[1]}, (h2){a[0], a[1]}, s, false);
    s = __builtin_amdgcn_fdot2((h2){v[2], v[3]}, (h2){a[2], a[3]}, s, false);
    s = __builtin_amdgcn_fdot2((h2){v[4], v[5]}, (h2){a[4], a[5]}, s, false);
    s = __builtin_amdgcn_fdot2((h2){v[6], v[7]}, (h2){a[6], a[7]}, s, false);
#else
#pragma unroll
    for (int k = 0; k < 8; ++k) s += (float)v[k] * (float)a[k];
#endif
    return s;
}

// x += x[other lane in 16-lane row], VALU-pipe DPP; ctrl must be a literal.
#define DPP_ADD(x, ctrl) \
    ((x) + __int_as_float(__builtin_amdgcn_update_dpp(0, __float_as_int(x), (ctrl), 0xF, 0xF, true)))

// ------- transpose+cast BOTH maps: [B, D, HW] f32 -> [B, HW, D] f16 -------
__global__ __launch_bounds__(256) void transpose_h_k(const float* __restrict__ f1,
                                                     const float* __restrict__ f2,
                                                     _Float16* __restrict__ o1,
                                                     _Float16* __restrict__ o2) {
    __shared__ float tile[64][33];
    const int z = blockIdx.z;               // z = map*2 + b
    const int b = z & 1;
    const float* in = (z >> 1) ? f2 : f1;
    _Float16* out = (z >> 1) ? o2 : o1;
    in += (size_t)b * DC * HWC;
    out += (size_t)b * HWC * DC;

    const int m0 = blockIdx.x * 32, d0 = blockIdx.y * 64;
    const int tid = threadIdx.x;
    const int tx = tid & 31, ty = tid >> 5;   // (m, d-octet)
#pragma unroll
    for (int k = 0; k < 8; ++k)
        tile[ty + k * 8][tx] = in[(size_t)(d0 + ty + k * 8) * HWC + m0 + tx];
    __syncthreads();

    const int dx = tid & 7, my = tid >> 3;    // (d-octet, m) — 2-way bank alias only
    h8 v;
#pragma unroll
    for (int e = 0; e < 8; ++e) v[e] = (_Float16)tile[dx * 8 + e][my];
    *(h8*)(out + (size_t)(m0 + my) * DC + d0 + dx * 8) = v;
}

// ---------------- fused neighborhood-corr + bilinear ----------------
// One block per pixel (b, hw). 16 groups x 16 lanes; each group owns one grid
// dot per iteration over the 10x10 integer patch. PHASE 1 issues all 14 patch
// b128 loads (clamped, unconditional) into registers; PHASE 2 does dots + DPP
// reduce. Validity AND the 1/sqrt(D) scale fold into one multiplier.
// RAFT quirk: out[n, i, j] samples at x = x_c + (i-4), y = y_c + (j-4).
__global__ __launch_bounds__(256) void corr_k(const _Float16* __restrict__ f1t,
                                              const _Float16* __restrict__ f2t,
                                              const float* __restrict__ coords,
                                              float* __restrict__ out) {
    __shared__ float Cs[112];   // Cs[yi*10+xi] = corr(y=iy0-4+yi, x=ix0-4+xi)

    const int bid = blockIdx.x;
    // XCD swizzle: batch 0 -> XCDs 0..3, batch 1 -> XCDs 4..7 (per-batch 4MB
    // f16 f2t fits the XCD group's L2)
    const int xcd = bid & 7;
    const int b = xcd >> 2;
    const int hw = ((bid >> 3) << 2) + (xcd & 3);

    const int tid = threadIdx.x;
    const int g = tid >> 4;    // group 0..15
    const int l = tid & 15;    // lane-in-group (= DPP row position)

    const float x = coords[((size_t)b * 2 + 0) * HWC + hw];
    const float y = coords[((size_t)b * 2 + 1) * HWC + hw];
    const float x0f = floorf(x), y0f = floorf(y);
    const float wx = x - x0f, wy = y - y0f;
    const int ix0 = (int)x0f, iy0 = (int)y0f;

    // f1 fragment: 16 consecutive d for this lane (same column for all groups)
    const h8* ap = (const h8*)f1t + ((size_t)(b * HWC + hw)) * 32 + l * 2;
    const h8 a0 = ap[0], a1 = ap[1];
    const h8* f2b = (const h8*)f2t + (size_t)b * HWC * 32;

    // ---- PHASE 1: issue all patch loads (static indices -> registers) ----
    h8 v0[7], v1[7];
    float vm[7];
#pragma unroll
    for (int it = 0; it < 7; ++it) {
        int t = it * 16 + g;
        t = t > 99 ? 99 : t;                    // dup cell 99 for the 12 pad slots
        const int yi = t / 10, xi = t - yi * 10;
        const int gy = iy0 - 4 + yi, gx = ix0 - 4 + xi;
        const bool valid = ((unsigned)gy < (unsigned)HC) & ((unsigned)gx < (unsigned)WC);
        const int gyc = min(max(gy, 0), HC - 1);
        const int gxc = min(max(gx, 0), WC - 1);
        const h8* vp = f2b + (size_t)(gyc * WC + gxc) * 32 + l * 2;
        v0[it] = vp[0];
        v1[it] = vp[1];
        vm[it] = valid ? 0.0625f : 0.f;         // validity * 1/sqrt(256)
    }

    // ---- PHASE 2: dots + in-wave 16-lane DPP reduce ----
#pragma unroll
    for (int it = 0; it < 7; ++it) {
        float s = dot8(v0[it], a0, 0.f);
        s = dot8(v1[it], a1, s);
        s *= vm[it];
        s = DPP_ADD(s, 0xB1);    // quad_perm [1,0,3,2]
        s = DPP_ADD(s, 0x4E);    // quad_perm [2,3,0,1]
        s = DPP_ADD(s, 0x124);   // row_ror:4
        s = DPP_ADD(s, 0x128);   // row_ror:8
        const int t = it * 16 + g;
        if (l == 0 && t < 100) Cs[t] = s;
    }
    __syncthreads();

    if (tid < KKC) {
        const int i = tid / 9, j = tid % 9;  // i walks x, j walks y (RAFT quirk)
        const float w00 = (1.f - wx) * (1.f - wy);
        const float w01 = wx * (1.f - wy);
        const float w10 = (1.f - wx) * wy;
        const float w11 = wx * wy;
        const float r = w00 * Cs[j * 10 + i]       + w01 * Cs[j * 10 + i + 1] +
                        w10 * Cs[(j + 1) * 10 + i] + w11 * Cs[(j + 1) * 10 + i + 1];
        out[((size_t)(b * KKC + tid)) * HWC + hw] = r;
    }
}

extern "C" void kernel_launch(void* const* d_in, const int* in_sizes, int n_in,
                              void* d_out, int out_size, void* d_ws, size_t ws_size,
                              hipStream_t stream) {
    const float* fmap1 = (const float*)d_in[0];
    const float* fmap2 = (const float*)d_in[1];
    const float* coords = (const float*)d_in[2];
    float* out = (float*)d_out;

    const size_t perH = (size_t)BC * HWC * DC;  // f16 elements per transposed map
    _Float16* f1t = (_Float16*)d_ws;
    _Float16* f2t = f1t + perH;

    transpose_h_k<<<dim3(HWC / 32, DC / 64, 4), dim3(256), 0, stream>>>(fmap1, fmap2, f1t, f2t);
    corr_k<<<dim3(BC * HWC), dim3(256), 0, stream>>>(f1t, f2t, coords, out);
}